// Round 7
// baseline (1372.245 us; speedup 1.0000x reference)
//
#include <hip/hip_runtime.h>

// LoRA forward: out = (h @ B^T) @ A^T, h: (16384, 4096) f32, rank 16.
// R7: fully fused pipeline. 256 blocks x 1024 thr, block = 64 rows = 4 tiles
// of 16. Per tile: 8 chunks (2 KB/row) h+B staged to LDS dbuf via
// global_load_lds (h source XOR-swizzled). Tile t's read loop interleaves
// tile t-1's NT stores (2 rows/iter) with EXACT counted vmcnt so stores and
// prefetch loads stay in flight together (never vmcnt(0) mid-loop). Reduces
// use raw s_barrier + lgkmcnt only (no vmcnt drain). A frag (64 f) in VGPRs.

constexpr int D      = 4096;
constexpr int RK     = 16;
constexpr int TROWS  = 16;          // rows per tile
constexpr int NTILES = 4;           // tiles per block (64 rows)
constexpr int CH     = 512;         // floats of d per chunk per row (2 KB)
constexpr int NCH    = D / CH;      // 8 chunks per tile
constexpr int NIT    = NTILES * NCH;  // 32 pipeline iterations

typedef float f32x4 __attribute__((ext_vector_type(4)));

__device__ __forceinline__ void gload_lds16(const float* src, float* ldsdst) {
  __builtin_amdgcn_global_load_lds(
      (const __attribute__((address_space(1))) void*)src,
      (__attribute__((address_space(3))) void*)ldsdst, 16, 0, 0);
}

__device__ __forceinline__ float dot4(float4 a, float4 b) {
  return a.x * b.x + a.y * b.y + a.z * b.z + a.w * b.w;
}

__global__ __launch_bounds__(1024, 1) void lora_fused(
    const float* __restrict__ h,
    const float* __restrict__ matA,   // (D, RK) row-major
    const float* __restrict__ matB,   // (RK, D) row-major
    float* __restrict__ out) {
  __shared__ float sH[2][TROWS][CH];      // 64 KB  h chunk dbuf (swizzled)
  __shared__ float sB[2][RK][CH];         // 64 KB  B chunk dbuf (linear)
  __shared__ float part[16][TROWS][RK];   // 16 KB  per-wave partials
  __shared__ float hr[2][TROWS][RK];      //  2 KB  hr ping-pong

  const int tid = threadIdx.x;
  const int w   = __builtin_amdgcn_readfirstlane(tid >> 6);  // wave 0..15
  const int l   = tid & 63;
  const int row = l & 15;               // my h-row within tile
  const int ss  = (w << 2) | (l >> 4);  // my d-subslice 0..63 (8 floats)
  const long row0 = (long)blockIdx.x * (NTILES * TROWS);

  // ---- A fragment: 4 contiguous output cols per thread, loaded once -------
  const int c0 = tid * 4;
  float4 a4[4][4];   // 64 VGPRs
#pragma unroll
  for (int j = 0; j < 4; ++j)
#pragma unroll
    for (int q = 0; q < 4; ++q)
      a4[j][q] = *reinterpret_cast<const float4*>(
          matA + (long)(c0 + j) * RK + q * 4);

  // ---- stage chunk for global iter gg into buffer b -----------------------
  // wave w stages h row w (2 x 1-KB halves, XOR-swizzled source) and B rank w
  // (2 halves, linear). 4 global_load_lds per wave per iter.
  auto STAGE = [&](int b, int gg) {
    const int t = gg >> 3, c = gg & 7;
    const float* hrow_p = h + (row0 + t * TROWS + w) * (long)D + c * CH;
    const float* brow_p = matB + (long)w * D + c * CH;
#pragma unroll
    for (int hf = 0; hf < 2; ++hf)
      gload_lds16(hrow_p + hf * 256 + ((l ^ (w & 7)) * 4), &sH[b][w][hf * 256]);
#pragma unroll
    for (int hf = 0; hf < 2; ++hf)
      gload_lds16(brow_p + hf * 256 + l * 4, &sB[b][w][hf * 256]);
  };

  float acc[RK];
#pragma unroll
  for (int r = 0; r < RK; ++r) acc[r] = 0.f;

  STAGE(0, 0);
#pragma unroll 1
  for (int g = 0; g < NIT; ++g) {
    const int t = g >> 3, c = g & 7;
    if (g + 1 < NIT) STAGE((g + 1) & 1, g + 1);

    // exact counted waits (in-order vmcnt retirement):
    //   g=31: [stores_30:2] after chunk-31 loads            -> vmcnt(2)
    //   g>=9: [stores_{g-1}:2][STAGE(g+1):4] after chunk g  -> vmcnt(6)
    //   else: [STAGE(g+1):4] after chunk g                  -> vmcnt(4)
    if (g == NIT - 1) {
      asm volatile("s_waitcnt vmcnt(2)" ::: "memory");
    } else if (g >= 9) {
      asm volatile("s_waitcnt vmcnt(6)" ::: "memory");
    } else {
      asm volatile("s_waitcnt vmcnt(4)" ::: "memory");
    }
    __builtin_amdgcn_s_barrier();
    __builtin_amdgcn_sched_barrier(0);

    // ---- stage-1 compute: row `row`, floats [ss*8, ss*8+8) of chunk ------
    const int buf = g & 1;
    float4 h4[2];
#pragma unroll
    for (int q = 0; q < 2; ++q)
      h4[q] = *reinterpret_cast<const float4*>(
          &sH[buf][row][((2 * ss + q) ^ (row & 7)) * 4]);  // deswizzle
#pragma unroll
    for (int r = 0; r < RK; ++r) {
      const float4 b0 =
          *reinterpret_cast<const float4*>(&sB[buf][r][ss * 8]);
      const float4 b1 =
          *reinterpret_cast<const float4*>(&sB[buf][r][ss * 8 + 4]);
      acc[r] += dot4(h4[0], b0) + dot4(h4[1], b1);
    }

    // ---- interleaved NT stores: rows 2c, 2c+1 of tile t-1 ----------------
    if (t >= 1) {
      const int hb = (t - 1) & 1;
#pragma unroll
      for (int k = 0; k < 2; ++k) {
        const int sr = 2 * c + k;
        const float4* hv = reinterpret_cast<const float4*>(&hr[hb][sr][0]);
        const float4 h0 = hv[0], h1 = hv[1], h2 = hv[2], h3 = hv[3];
        f32x4 o;
        o.x = dot4(h0, a4[0][0]) + dot4(h1, a4[0][1]) + dot4(h2, a4[0][2]) +
              dot4(h3, a4[0][3]);
        o.y = dot4(h0, a4[1][0]) + dot4(h1, a4[1][1]) + dot4(h2, a4[1][2]) +
              dot4(h3, a4[1][3]);
        o.z = dot4(h0, a4[2][0]) + dot4(h1, a4[2][1]) + dot4(h2, a4[2][2]) +
              dot4(h3, a4[2][3]);
        o.w = dot4(h0, a4[3][0]) + dot4(h1, a4[3][1]) + dot4(h2, a4[3][2]) +
              dot4(h3, a4[3][3]);
        __builtin_nontemporal_store(
            o, reinterpret_cast<f32x4*>(
                   out + (row0 + (t - 1) * TROWS + sr) * (long)D + c0));
      }
    }

    asm volatile("" ::: "memory");
    __builtin_amdgcn_s_barrier();   // computes done before buf overwrite
    __builtin_amdgcn_sched_barrier(0);

    // ---- tile boundary: reduce partials -> hr[t&1] (lgkm-only syncs) -----
    if (c == NCH - 1) {
#pragma unroll
      for (int r = 0; r < RK; ++r) {
        acc[r] += __shfl_xor(acc[r], 16, 64);
        acc[r] += __shfl_xor(acc[r], 32, 64);
      }
      if (l < TROWS) {
#pragma unroll
        for (int r = 0; r < RK; ++r) part[w][l][r] = acc[r];
      }
      asm volatile("s_waitcnt lgkmcnt(0)" ::: "memory");
      __builtin_amdgcn_s_barrier();
      __builtin_amdgcn_sched_barrier(0);
      if (tid < 256) {
        const int orow = tid >> 4, rk = tid & 15;
        float s = 0.f;
#pragma unroll
        for (int w2 = 0; w2 < 16; ++w2) s += part[w2][orow][rk];
        hr[t & 1][orow][rk] = s;
      }
      asm volatile("s_waitcnt lgkmcnt(0)" ::: "memory");
      __builtin_amdgcn_s_barrier();
      __builtin_amdgcn_sched_barrier(0);
#pragma unroll
      for (int r = 0; r < RK; ++r) acc[r] = 0.f;
    }
  }

  // ---- tail: store tile NTILES-1 (reads hr[(NTILES-1)&1]) -----------------
  const int hb = (NTILES - 1) & 1;
#pragma unroll 4
  for (int sr = 0; sr < TROWS; ++sr) {
    const float4* hv = reinterpret_cast<const float4*>(&hr[hb][sr][0]);
    const float4 h0 = hv[0], h1 = hv[1], h2 = hv[2], h3 = hv[3];
    f32x4 o;
    o.x = dot4(h0, a4[0][0]) + dot4(h1, a4[0][1]) + dot4(h2, a4[0][2]) +
          dot4(h3, a4[0][3]);
    o.y = dot4(h0, a4[1][0]) + dot4(h1, a4[1][1]) + dot4(h2, a4[1][2]) +
          dot4(h3, a4[1][3]);
    o.z = dot4(h0, a4[2][0]) + dot4(h1, a4[2][1]) + dot4(h2, a4[2][2]) +
          dot4(h3, a4[2][3]);
    o.w = dot4(h0, a4[3][0]) + dot4(h1, a4[3][1]) + dot4(h2, a4[3][2]) +
          dot4(h3, a4[3][3]);
    __builtin_nontemporal_store(
        o, reinterpret_cast<f32x4*>(
               out + (row0 + (NTILES - 1) * TROWS + sr) * (long)D + c0));
  }
}

extern "C" void kernel_launch(void* const* d_in, const int* in_sizes, int n_in,
                              void* d_out, int out_size, void* d_ws,
                              size_t ws_size, hipStream_t stream) {
  const float* h    = (const float*)d_in[0];
  const float* matA = (const float*)d_in[1];
  const float* matB = (const float*)d_in[2];
  float* out        = (float*)d_out;

  const long M = (long)in_sizes[0] / D;               // 16384 rows
  const int nblocks = (int)(M / (NTILES * TROWS));    // 256 blocks, 1/CU
  hipLaunchKernelGGL(lora_fused, dim3(nblocks), dim3(1024), 0, stream,
                     h, matA, matB, out);
}

// Round 8
// 278.100 us; speedup vs baseline: 4.9344x; 4.9344x over previous
//
#include <hip/hip_runtime.h>

// LoRA forward: out = (h @ B^T) @ A^T, h: (16384, 4096) f32, rank 16.
// R8: two-kernel split (R5 structure) with K1 rebuilt around lane=row:
//  K1: 512 blocks x 256 thr (4 waves). Block = 64 rows x d-half (2048).
//      16 chunks of 128 floats/row; h staged to LDS dbuf (32 KB x2) via
//      global_load_lds w=16 with 32-slot XOR-swizzled SOURCE (read is 2-way
//      bank aliased = free). B via WAVE-UNIFORM scalar loads (wave w owns a
//      32-float d-slice per chunk; lane l owns row l) -> zero LDS for B.
//      Each wave streams its partial straight to d_ws (8 partials total);
//      no cross-wave reduction in K1.
//  K2: out = (sum of 8 partials) @ A^T. A fragment in VGPRs (only big reg
//      object -> no spill), uniform hrp loads, NT float4 stores.

constexpr int  D  = 4096;
constexpr int  RK = 16;
constexpr long M  = 16384;

typedef float f32x4 __attribute__((ext_vector_type(4)));

__device__ __forceinline__ void gload_lds16(const float* src, float* ldsdst) {
  __builtin_amdgcn_global_load_lds(
      (const __attribute__((address_space(1))) void*)src,
      (__attribute__((address_space(3))) void*)ldsdst, 16, 0, 0);
}

__device__ __forceinline__ float dot4(float4 a, float4 b) {
  return a.x * b.x + a.y * b.y + a.z * b.z + a.w * b.w;
}

// ---------------------------------------------------------------- K1 -------
constexpr int K1_CH  = 128;            // floats of d per chunk per row (512 B)
constexpr int K1_NCH = 2048 / K1_CH;   // 16 chunks per d-half

__global__ __launch_bounds__(256) void lora_k1(
    const float* __restrict__ h,
    const float* __restrict__ matB,    // (RK, D) row-major
    float* __restrict__ hrp) {         // (8, M, RK) partials
  __shared__ float sH[2][64][K1_CH];   // 64 KB dbuf, 512 B per row

  const int tid  = threadIdx.x;
  const int w    = __builtin_amdgcn_readfirstlane(tid >> 6);  // wave 0..3
  const int l    = tid & 63;                                  // lane = row
  const long row0 = (long)(blockIdx.x >> 1) * 64;
  const int  half = blockIdx.x & 1;
  const int  dbase = half * 2048;

  // Per chunk: 64 rows x 512 B = 32 wave-loads of 1 KB; wave w issues 8.
  // Load i covers rows 2i, 2i+1; lane l -> row 2i+(l>>5), 16-B slot l&31.
  // Swizzle in SOURCE: LDS[R][sd] <- h[R][sd ^ (R & 31)]  (dest linear).
  auto STAGE = [&](int b, int c) {
#pragma unroll
    for (int j = 0; j < 8; ++j) {
      const int i  = w * 8 + j;
      const int R  = 2 * i + (l >> 5);
      const int sd = l & 31;
      const float* src = h + (row0 + R) * (long)D + dbase + c * K1_CH +
                         ((sd ^ (R & 31)) * 4);
      gload_lds16(src, &sH[b][2 * i][0]);
    }
  };

  float acc[RK];
#pragma unroll
  for (int r = 0; r < RK; ++r) acc[r] = 0.f;

  STAGE(0, 0);
#pragma unroll 1
  for (int c = 0; c < K1_NCH; ++c) {
    if (c + 1 < K1_NCH) {
      STAGE((c + 1) & 1, c + 1);
      asm volatile("s_waitcnt vmcnt(8)" ::: "memory");  // chunk c landed
    } else {
      asm volatile("s_waitcnt vmcnt(0)" ::: "memory");
    }
    __builtin_amdgcn_s_barrier();
    __builtin_amdgcn_sched_barrier(0);

    // thread (w,l): row l, d-slice w*32 .. w*32+32 of this chunk
    const int buf = c & 1;
    float4 h4[8];
#pragma unroll
    for (int q = 0; q < 8; ++q) {
      const int slot = (w * 8 + q) ^ (l & 31);   // deswizzle
      h4[q] = *reinterpret_cast<const float4*>(&sH[buf][l][slot * 4]);
    }

    const float* bbase = matB + dbase + c * K1_CH + w * 32;  // wave-uniform
#pragma unroll
    for (int r = 0; r < RK; ++r) {
      const float* br = bbase + (long)r * D;
      float s = 0.f;
#pragma unroll
      for (int q = 0; q < 8; ++q)
        s += dot4(h4[q], *reinterpret_cast<const float4*>(br + q * 4));
      acc[r] += s;
    }
    asm volatile("" ::: "memory");
    __builtin_amdgcn_s_barrier();   // computes done before buf overwrite
    __builtin_amdgcn_sched_barrier(0);
  }

  // wave-private partial -> ws (plain stores: keep L2-resident for K2)
  float* dst = hrp + ((long)(half * 4 + w) * M + row0 + l) * RK;
#pragma unroll
  for (int q = 0; q < 4; ++q)
    *reinterpret_cast<f32x4*>(dst + q * 4) =
        *reinterpret_cast<const f32x4*>(&acc[q * 4]);
}

// ---------------------------------------------------------------- K2 -------
__global__ __launch_bounds__(256) void lora_k2(
    const float* __restrict__ hrp,    // (8, M, RK)
    const float* __restrict__ matA,   // (D, RK) row-major
    float* __restrict__ out) {
  const int tid = threadIdx.x;
  const int cs  = blockIdx.x & 3;          // column slice (1024 cols)
  const long row0 = (long)(blockIdx.x >> 2) * 64;
  const int c0 = cs * 1024 + tid * 4;      // 4 contiguous cols per thread

  float4 a[4][4];  // A rows for my 4 cols: 64 VGPRs, reused 64x
#pragma unroll
  for (int j = 0; j < 4; ++j)
#pragma unroll
    for (int q = 0; q < 4; ++q)
      a[j][q] = *reinterpret_cast<const float4*>(
          matA + (long)(c0 + j) * RK + q * 4);

#pragma unroll 4
  for (int rr = 0; rr < 64; ++rr) {
    const long row = row0 + rr;
    float4 hs[4];
#pragma unroll
    for (int q = 0; q < 4; ++q) hs[q] = make_float4(0.f, 0.f, 0.f, 0.f);
#pragma unroll
    for (int p = 0; p < 8; ++p) {
      const float4* hv =
          reinterpret_cast<const float4*>(hrp + ((long)p * M + row) * RK);
#pragma unroll
      for (int q = 0; q < 4; ++q) {
        const float4 v = hv[q];
        hs[q].x += v.x; hs[q].y += v.y; hs[q].z += v.z; hs[q].w += v.w;
      }
    }
    f32x4 o;
    o.x = dot4(hs[0], a[0][0]) + dot4(hs[1], a[0][1]) + dot4(hs[2], a[0][2]) +
          dot4(hs[3], a[0][3]);
    o.y = dot4(hs[0], a[1][0]) + dot4(hs[1], a[1][1]) + dot4(hs[2], a[1][2]) +
          dot4(hs[3], a[1][3]);
    o.z = dot4(hs[0], a[2][0]) + dot4(hs[1], a[2][1]) + dot4(hs[2], a[2][2]) +
          dot4(hs[3], a[2][3]);
    o.w = dot4(hs[0], a[3][0]) + dot4(hs[1], a[3][1]) + dot4(hs[2], a[3][2]) +
          dot4(hs[3], a[3][3]);
    __builtin_nontemporal_store(
        o, reinterpret_cast<f32x4*>(out + row * (long)D + c0));
  }
}

extern "C" void kernel_launch(void* const* d_in, const int* in_sizes, int n_in,
                              void* d_out, int out_size, void* d_ws,
                              size_t ws_size, hipStream_t stream) {
  const float* h    = (const float*)d_in[0];
  const float* matA = (const float*)d_in[1];
  const float* matB = (const float*)d_in[2];
  float* out        = (float*)d_out;
  float* hrp        = (float*)d_ws;   // 8 * M * RK * 4 = 8 MiB scratch

  hipLaunchKernelGGL(lora_k1, dim3((int)(M / 64) * 2), dim3(256), 0, stream,
                     h, matB, hrp);
  hipLaunchKernelGGL(lora_k2, dim3((int)(M / 64) * 4), dim3(256), 0, stream,
                     hrp, matA, out);
}